// Round 2
// baseline (537.086 us; speedup 1.0000x reference)
//
#include <hip/hip_runtime.h>
#include <hip/hip_bf16.h>

#define N_NODES 50000
#define N_EDGES 800000
#define D 64

typedef __hip_bfloat16 bf16;

__device__ __forceinline__ float b2f(bf16 v) { return __bfloat162float(v); }

// dual-dtype float load: f32mode ? f32[i] : bf16[i]
__device__ __forceinline__ float ldf(const void* p, size_t i, bool f32mode) {
    if (f32mode) return ((const float*)p)[i];
    return b2f(((const bf16*)p)[i]);
}
__device__ __forceinline__ void stf(void* p, size_t i, float v, bool f32mode) {
    if (f32mode) ((float*)p)[i] = v;
    else ((bf16*)p)[i] = __float2bfloat16(v);
}
// dual-width index load: row 0 = src, row 1 = dst
__device__ __forceinline__ int ldidx(const int* ei, size_t e, int row, bool i64mode) {
    if (i64mode) return ei[((size_t)row * N_EDGES + e) * 2];  // low word, little-endian
    return ei[(size_t)row * N_EDGES + e];
}

// ---------------------------------------------------------------------------
// Kernel 0: runtime dtype detection (graph-safe, recomputed every launch).
// flags[0]: 1 = floats are f32, 0 = bf16. flags[1]: 1 = indices int64, 0 = int32.
// bf16 is the top half of f32, so packed-f32 read as bf16 has random-exponent
// garbage in EVEN slots; true bf16 N(0,1) data has exponents ~127+-20.
// int64 indices (<2^31) read as int32 pairs have all-zero ODD words.
// ---------------------------------------------------------------------------
__global__ void detect_kernel(const void* __restrict__ x,
                              const int* __restrict__ ei,
                              int* __restrict__ flags)
{
    if (blockIdx.x != 0 || threadIdx.x != 0) return;
    const unsigned short* u = (const unsigned short*)x;
    int weird = 0;
    for (int k = 0; k < 128; ++k) {
        int ex = (u[2 * k] >> 7) & 0xFF;
        if (ex < 90 || ex > 160) ++weird;   // |v| outside ~[2^-37, 2^33]
    }
    flags[0] = (weird > 32) ? 1 : 0;
    int zeros = 0;
    for (int k = 0; k < 128; ++k) if (ei[2 * k + 1] == 0) ++zeros;
    flags[1] = (zeros > 120) ? 1 : 0;
}

// ---------------------------------------------------------------------------
// Kernel 1: scatter-add  agg[dst[e]*D + d] += x[src[e]*D + d]
// One wave per edge (lane = feature d).
// ---------------------------------------------------------------------------
__global__ __launch_bounds__(256) void scatter_kernel(
    const void* __restrict__ x, const int* __restrict__ ei,
    float* __restrict__ agg, const int* __restrict__ flags)
{
    bool f32m = flags[0] != 0;
    bool i64m = flags[1] != 0;
    long long t = (long long)blockIdx.x * 256 + threadIdx.x;
    int e = (int)(t >> 6);
    int d = (int)(t & 63);
    if (e >= N_EDGES) return;
    int s  = ldidx(ei, e, 0, i64m);
    int dd = ldidx(ei, e, 1, i64m);
    float v = ldf(x, (size_t)s * D + d, f32m);
    atomicAdd(&agg[(size_t)dd * D + d], v);
}

// ---------------------------------------------------------------------------
// Kernel 2 (fused): per node n
//   emb      = relu((x[n] + agg[n]) @ W_enc + b_enc)
//   p_src[n] = emb @ W1[0:64,:]   (f32 out)
//   p_dst[n] = emb @ W1[64:128,:] (f32 out)
// Weights staged once per block in LDS as f32. 4 waves/block = 4 nodes.
// ---------------------------------------------------------------------------
__global__ __launch_bounds__(256) void node_kernel(
    const void* __restrict__ x, const float* __restrict__ agg,
    const void* __restrict__ W_enc, const void* __restrict__ b_enc,
    const void* __restrict__ W1,
    float* __restrict__ p_src, float* __restrict__ p_dst,
    const int* __restrict__ flags)
{
    __shared__ float We[64 * 64];
    __shared__ float Wa[64 * 64];
    __shared__ float Wb[64 * 64];
    __shared__ float be[64];
    __shared__ float vbuf[4][64];
    __shared__ float ebuf[4][64];

    bool f32m = flags[0] != 0;
    int tid = threadIdx.x;
    for (int i = tid; i < 4096; i += 256) {
        We[i] = ldf(W_enc, i, f32m);
        Wa[i] = ldf(W1, i, f32m);
        Wb[i] = ldf(W1, 4096 + i, f32m);
    }
    if (tid < 64) be[tid] = ldf(b_enc, tid, f32m);
    __syncthreads();

    int wave = tid >> 6;
    int lane = tid & 63;
    int n = blockIdx.x * 4 + wave;
    bool ok = (n < N_NODES);

    if (ok) vbuf[wave][lane] = ldf(x, (size_t)n * D + lane, f32m) + agg[(size_t)n * D + lane];
    __syncthreads();

    if (ok) {
        float acc = be[lane];
        #pragma unroll
        for (int i = 0; i < 64; ++i) acc += vbuf[wave][i] * We[i * 64 + lane];
        ebuf[wave][lane] = fmaxf(acc, 0.f);
    }
    __syncthreads();

    if (ok) {
        float ps = 0.f, pd = 0.f;
        #pragma unroll
        for (int i = 0; i < 64; ++i) {
            float ev = ebuf[wave][i];
            ps += ev * Wa[i * 64 + lane];
            pd += ev * Wb[i * 64 + lane];
        }
        p_src[(size_t)n * D + lane] = ps;
        p_dst[(size_t)n * D + lane] = pd;
    }
}

// ---------------------------------------------------------------------------
// Kernel 3: per edge e (one wave per edge, lane = hidden unit k):
//   h_k = relu(p_src[src[e]][k] + p_dst[dst[e]][k] + b1[k])
//   out[e] = sum_k h_k * W2[k] + b2     (shuffle reduce)
// ---------------------------------------------------------------------------
__global__ __launch_bounds__(256) void edge_kernel(
    const int* __restrict__ ei,
    const float* __restrict__ p_src, const float* __restrict__ p_dst,
    const void* __restrict__ b1, const void* __restrict__ W2,
    const void* __restrict__ b2,
    void* __restrict__ out, const int* __restrict__ flags)
{
    bool f32m = flags[0] != 0;
    bool i64m = flags[1] != 0;
    long long t = (long long)blockIdx.x * 256 + threadIdx.x;
    int e = (int)(t >> 6);
    int lane = (int)(t & 63);
    if (e >= N_EDGES) return;

    int s  = ldidx(ei, e, 0, i64m);
    int dd = ldidx(ei, e, 1, i64m);
    float h = p_src[(size_t)s * D + lane]
            + p_dst[(size_t)dd * D + lane]
            + ldf(b1, lane, f32m);
    h = fmaxf(h, 0.f);
    float c = h * ldf(W2, lane, f32m);

    #pragma unroll
    for (int off = 32; off > 0; off >>= 1)
        c += __shfl_down(c, off, 64);

    if (lane == 0) stf(out, e, c + ldf(b2, 0, f32m), f32m);
}

// ---------------------------------------------------------------------------
extern "C" void kernel_launch(void* const* d_in, const int* in_sizes, int n_in,
                              void* d_out, int out_size, void* d_ws, size_t ws_size,
                              hipStream_t stream)
{
    const void* x     = d_in[0];
    const int*  ei    = (const int*)d_in[1];
    const void* W_enc = d_in[2];
    const void* b_enc = d_in[3];
    const void* W1    = d_in[4];
    const void* b1    = d_in[5];
    const void* W2    = d_in[6];
    const void* b2    = d_in[7];

    // ws layout: agg f32[3.2M] | p_src f32[3.2M] | p_dst f32[3.2M] | flags int[2]
    const size_t NT = (size_t)N_NODES * D;
    float* agg   = (float*)d_ws;
    float* p_src = agg + NT;
    float* p_dst = p_src + NT;
    int*   flags = (int*)(p_dst + NT);

    detect_kernel<<<1, 64, 0, stream>>>(x, ei, flags);
    hipMemsetAsync(agg, 0, NT * sizeof(float), stream);

    int eblocks = (int)(((long long)N_EDGES * 64 + 255) / 256);
    scatter_kernel<<<eblocks, 256, 0, stream>>>(x, ei, agg, flags);
    node_kernel<<<(N_NODES + 3) / 4, 256, 0, stream>>>(x, agg, W_enc, b_enc, W1,
                                                       p_src, p_dst, flags);
    edge_kernel<<<eblocks, 256, 0, stream>>>(ei, p_src, p_dst, b1, W2, b2,
                                             d_out, flags);
}

// Round 3
// 529.614 us; speedup vs baseline: 1.0141x; 1.0141x over previous
//
#include <hip/hip_runtime.h>
#include <hip/hip_bf16.h>

#define N_NODES 50000
#define N_EDGES 800000
#define D 64

typedef __hip_bfloat16 bf16;
typedef __bf16 bf16x8 __attribute__((ext_vector_type(8)));
typedef float  f32x4  __attribute__((ext_vector_type(4)));

__device__ __forceinline__ float b2f(bf16 v) { return __bfloat162float(v); }
__device__ __forceinline__ float bu2f(unsigned short u) {
    unsigned int w = ((unsigned int)u) << 16;
    return __builtin_bit_cast(float, w);
}
__device__ __forceinline__ unsigned short f2bu(float f) {
    bf16 h = __float2bfloat16(f);           // RTNE
    return __builtin_bit_cast(unsigned short, h);
}
// dual-dtype float load: f32mode ? f32[i] : bf16[i]
__device__ __forceinline__ float ldf(const void* p, size_t i, bool f32mode) {
    if (f32mode) return ((const float*)p)[i];
    return b2f(((const bf16*)p)[i]);
}
__device__ __forceinline__ void stf(void* p, size_t i, float v, bool f32mode) {
    if (f32mode) ((float*)p)[i] = v;
    else ((bf16*)p)[i] = __float2bfloat16(v);
}
// dual-width index load: row 0 = src, row 1 = dst
__device__ __forceinline__ int ldidx(const int* ei, size_t e, int row, bool i64mode) {
    if (i64mode) return ei[((size_t)row * N_EDGES + e) * 2];  // low word, LE
    return ei[(size_t)row * N_EDGES + e];
}

// ---------------------------------------------------------------------------
// Kernel 0: runtime dtype detection (proven in R2). flags[0]=f32?, flags[1]=i64?
// ---------------------------------------------------------------------------
__global__ void detect_kernel(const void* __restrict__ x,
                              const int* __restrict__ ei,
                              int* __restrict__ flags)
{
    if (blockIdx.x != 0 || threadIdx.x != 0) return;
    const unsigned short* u = (const unsigned short*)x;
    int weird = 0;
    for (int k = 0; k < 128; ++k) {
        int ex = (u[2 * k] >> 7) & 0xFF;
        if (ex < 90 || ex > 160) ++weird;
    }
    flags[0] = (weird > 32) ? 1 : 0;
    int zeros = 0;
    for (int k = 0; k < 128; ++k) if (ei[2 * k + 1] == 0) ++zeros;
    flags[1] = (zeros > 120) ? 1 : 0;
}

// ---------------------------------------------------------------------------
// Kernel 1: in-degree histogram (int atomics on 200KB L2-resident table)
// ---------------------------------------------------------------------------
__global__ __launch_bounds__(256) void hist_kernel(
    const int* __restrict__ ei, int* __restrict__ counts,
    const int* __restrict__ flags)
{
    bool i64m = flags[1] != 0;
    int e = blockIdx.x * 256 + threadIdx.x;
    if (e >= N_EDGES) return;
    atomicAdd(&counts[ldidx(ei, e, 1, i64m)], 1);
}

// ---------------------------------------------------------------------------
// Kernel 2: single-block exclusive scan of counts[50000] -> offsets, cursor
// ---------------------------------------------------------------------------
__global__ __launch_bounds__(1024) void scan_kernel(
    const int* __restrict__ counts, int* __restrict__ offsets,
    int* __restrict__ cursor)
{
    __shared__ int sums[1024];
    const int CHUNK = 49;   // 1024*49 = 50176 >= 50000
    int tid = threadIdx.x;
    int start = tid * CHUNK;
    int end   = min(start + CHUNK, N_NODES);
    int local = 0;
    for (int i = start; i < end; ++i) local += counts[i];
    sums[tid] = local;
    __syncthreads();
    // Hillis-Steele inclusive scan (double barrier)
    for (int off = 1; off < 1024; off <<= 1) {
        int v = (tid >= off) ? sums[tid - off] : 0;
        __syncthreads();
        if (tid >= off) sums[tid] += v;
        __syncthreads();
    }
    int run = sums[tid] - local;   // exclusive prefix for this chunk
    for (int i = start; i < end; ++i) {
        offsets[i] = run;
        cursor[i]  = run;
        run += counts[i];
    }
    if (tid == 1023) offsets[N_NODES] = sums[1023];
}

// ---------------------------------------------------------------------------
// Kernel 3: bucket fill — bucket[pos] = src(e), grouped by dst(e)
// ---------------------------------------------------------------------------
__global__ __launch_bounds__(256) void fill_kernel(
    const int* __restrict__ ei, int* __restrict__ cursor,
    int* __restrict__ bucket, const int* __restrict__ flags)
{
    bool i64m = flags[1] != 0;
    int e = blockIdx.x * 256 + threadIdx.x;
    if (e >= N_EDGES) return;
    int s = ldidx(ei, e, 0, i64m);
    int d = ldidx(ei, e, 1, i64m);
    int pos = atomicAdd(&cursor[d], 1);
    bucket[pos] = s;
}

// ---------------------------------------------------------------------------
// Kernel 4 (fused gather + MFMA node stage): one wave = 16 nodes.
//   v[n]   = x[n] + sum_{s in bucket range} x[s]         (f32 acc, lane=feat)
//   emb    = relu(V @ W_enc + b_enc)                     (mfma 16x16x32 bf16)
//   p_src  = emb @ W1[0:64], p_dst = emb @ W1[64:128]    (mfma, bf16 out)
// Weights staged per block as B-fragment-friendly transposed LDS (Wt[n][k]).
// ---------------------------------------------------------------------------
__global__ __launch_bounds__(256) void node_kernel(
    const void* __restrict__ x,
    const int* __restrict__ offsets, const int* __restrict__ bucket,
    const void* __restrict__ W_enc, const void* __restrict__ b_enc,
    const void* __restrict__ W1,
    unsigned short* __restrict__ p_src, unsigned short* __restrict__ p_dst,
    const int* __restrict__ flags)
{
    // Wt stride 72 elem (144 B): 16B-aligned rows, spreads banks
    __shared__ unsigned short wtWe[64 * 72];
    __shared__ unsigned short wtWa[64 * 72];
    __shared__ unsigned short wtWb[64 * 72];
    __shared__ float benc[64];
    __shared__ unsigned short vbuf[4][16 * 72];
    __shared__ unsigned short ebuf[4][16 * 72];

    bool f32m = flags[0] != 0;
    int tid = threadIdx.x;

    for (int t = tid; t < 4096; t += 256) {
        int i = t >> 6, j = t & 63;             // W[i][j], i=k(in), j=n(out)
        wtWe[j * 72 + i] = f2bu(ldf(W_enc, t, f32m));
        wtWa[j * 72 + i] = f2bu(ldf(W1, t, f32m));
        wtWb[j * 72 + i] = f2bu(ldf(W1, 4096 + t, f32m));
    }
    if (tid < 64) benc[tid] = ldf(b_enc, tid, f32m);
    __syncthreads();

    int wave = tid >> 6;
    int lane = tid & 63;
    int lo   = lane & 15;
    int quad = lane >> 4;
    unsigned short* vb = vbuf[wave];
    unsigned short* eb = ebuf[wave];

    int base = blockIdx.x * 64 + wave * 16;     // first node of this wave

    // ---- gather + build A_v (lane = feature) ----
    for (int mm = 0; mm < 16; ++mm) {
        int n = base + mm;
        float acc = 0.f;
        if (n < N_NODES) {
            acc = ldf(x, (size_t)n * D + lane, f32m);
            int beg = offsets[n], end = offsets[n + 1];
            int j = beg;
            for (; j + 4 <= end; j += 4) {
                int s0 = bucket[j], s1 = bucket[j + 1];
                int s2 = bucket[j + 2], s3 = bucket[j + 3];
                float a0 = ldf(x, (size_t)s0 * D + lane, f32m);
                float a1 = ldf(x, (size_t)s1 * D + lane, f32m);
                float a2 = ldf(x, (size_t)s2 * D + lane, f32m);
                float a3 = ldf(x, (size_t)s3 * D + lane, f32m);
                acc += (a0 + a1) + (a2 + a3);
            }
            for (; j < end; ++j)
                acc += ldf(x, (size_t)bucket[j] * D + lane, f32m);
        }
        vb[mm * 72 + lane] = f2bu(acc);
    }

    // ---- matmul 1: E = relu(V @ We + b) ----
    bf16x8 av0 = *(const bf16x8*)&vb[lo * 72 + quad * 8];
    bf16x8 av1 = *(const bf16x8*)&vb[lo * 72 + 32 + quad * 8];

    f32x4 z = {0.f, 0.f, 0.f, 0.f};
    f32x4 acc1[4] = {z, z, z, z};
    #pragma unroll
    for (int nt = 0; nt < 4; ++nt) {
        bf16x8 b0 = *(const bf16x8*)&wtWe[(nt * 16 + lo) * 72 + quad * 8];
        bf16x8 b1 = *(const bf16x8*)&wtWe[(nt * 16 + lo) * 72 + 32 + quad * 8];
        acc1[nt] = __builtin_amdgcn_mfma_f32_16x16x32_bf16(av0, b0, acc1[nt], 0, 0, 0);
        acc1[nt] = __builtin_amdgcn_mfma_f32_16x16x32_bf16(av1, b1, acc1[nt], 0, 0, 0);
    }
    // epilogue 1: bias + relu, write E to LDS (C-layout: m=quad*4+r, n=nt*16+lo)
    #pragma unroll
    for (int nt = 0; nt < 4; ++nt) {
        float bias = benc[nt * 16 + lo];
        #pragma unroll
        for (int r = 0; r < 4; ++r) {
            int m = quad * 4 + r;
            float ev = fmaxf(acc1[nt][r] + bias, 0.f);
            eb[m * 72 + nt * 16 + lo] = f2bu(ev);
        }
    }

    // ---- matmuls 2,3: P_src = E @ Wa, P_dst = E @ Wb ----
    bf16x8 ae0 = *(const bf16x8*)&eb[lo * 72 + quad * 8];
    bf16x8 ae1 = *(const bf16x8*)&eb[lo * 72 + 32 + quad * 8];

    f32x4 acc2[4] = {z, z, z, z};
    f32x4 acc3[4] = {z, z, z, z};
    #pragma unroll
    for (int nt = 0; nt < 4; ++nt) {
        bf16x8 ba0 = *(const bf16x8*)&wtWa[(nt * 16 + lo) * 72 + quad * 8];
        bf16x8 ba1 = *(const bf16x8*)&wtWa[(nt * 16 + lo) * 72 + 32 + quad * 8];
        bf16x8 bb0 = *(const bf16x8*)&wtWb[(nt * 16 + lo) * 72 + quad * 8];
        bf16x8 bb1 = *(const bf16x8*)&wtWb[(nt * 16 + lo) * 72 + 32 + quad * 8];
        acc2[nt] = __builtin_amdgcn_mfma_f32_16x16x32_bf16(ae0, ba0, acc2[nt], 0, 0, 0);
        acc2[nt] = __builtin_amdgcn_mfma_f32_16x16x32_bf16(ae1, ba1, acc2[nt], 0, 0, 0);
        acc3[nt] = __builtin_amdgcn_mfma_f32_16x16x32_bf16(ae0, bb0, acc3[nt], 0, 0, 0);
        acc3[nt] = __builtin_amdgcn_mfma_f32_16x16x32_bf16(ae1, bb1, acc3[nt], 0, 0, 0);
    }
    // epilogue 2: store p tables (bf16)
    #pragma unroll
    for (int nt = 0; nt < 4; ++nt) {
        #pragma unroll
        for (int r = 0; r < 4; ++r) {
            int node = base + quad * 4 + r;
            if (node < N_NODES) {
                size_t idx = (size_t)node * D + nt * 16 + lo;
                p_src[idx] = f2bu(acc2[nt][r]);
                p_dst[idx] = f2bu(acc3[nt][r]);
            }
        }
    }
}

// ---------------------------------------------------------------------------
// Kernel 5: edge scorer — 16 lanes per edge (4 edges/wave), ushort4 loads.
//   h = relu(p_src[s] + p_dst[d] + b1); out[e] = h . W2 + b2
// ---------------------------------------------------------------------------
__global__ __launch_bounds__(256) void edge_kernel(
    const int* __restrict__ ei,
    const unsigned short* __restrict__ p_src,
    const unsigned short* __restrict__ p_dst,
    const void* __restrict__ b1, const void* __restrict__ W2,
    const void* __restrict__ b2,
    void* __restrict__ out, const int* __restrict__ flags)
{
    bool f32m = flags[0] != 0;
    bool i64m = flags[1] != 0;
    long long t = (long long)blockIdx.x * 256 + threadIdx.x;
    int e   = (int)(t >> 4);
    int sub = (int)(t & 15);
    if (e >= N_EDGES) return;

    int s = ldidx(ei, e, 0, i64m);
    int d = ldidx(ei, e, 1, i64m);

    ushort4 a = ((const ushort4*)p_src)[(size_t)s * 16 + sub];
    ushort4 b = ((const ushort4*)p_dst)[(size_t)d * 16 + sub];

    int f = sub * 4;
    float c = 0.f;
    {
        float h0 = fmaxf(bu2f(a.x) + bu2f(b.x) + ldf(b1, f + 0, f32m), 0.f);
        float h1 = fmaxf(bu2f(a.y) + bu2f(b.y) + ldf(b1, f + 1, f32m), 0.f);
        float h2 = fmaxf(bu2f(a.z) + bu2f(b.z) + ldf(b1, f + 2, f32m), 0.f);
        float h3 = fmaxf(bu2f(a.w) + bu2f(b.w) + ldf(b1, f + 3, f32m), 0.f);
        c = h0 * ldf(W2, f + 0, f32m) + h1 * ldf(W2, f + 1, f32m)
          + h2 * ldf(W2, f + 2, f32m) + h3 * ldf(W2, f + 3, f32m);
    }
    // reduce across the 16-lane group
    c += __shfl_xor(c, 1, 64);
    c += __shfl_xor(c, 2, 64);
    c += __shfl_xor(c, 4, 64);
    c += __shfl_xor(c, 8, 64);

    if (sub == 0) stf(out, e, c + ldf(b2, 0, f32m), f32m);
}

// ---------------------------------------------------------------------------
extern "C" void kernel_launch(void* const* d_in, const int* in_sizes, int n_in,
                              void* d_out, int out_size, void* d_ws, size_t ws_size,
                              hipStream_t stream)
{
    const void* x     = d_in[0];
    const int*  ei    = (const int*)d_in[1];
    const void* W_enc = d_in[2];
    const void* b_enc = d_in[3];
    const void* W1    = d_in[4];
    const void* b1    = d_in[5];
    const void* W2    = d_in[6];
    const void* b2    = d_in[7];

    const size_t NT = (size_t)N_NODES * D;   // 3.2M elements
    // ws layout:
    unsigned short* p_src = (unsigned short*)d_ws;            // 6.4 MB
    unsigned short* p_dst = p_src + NT;                       // 6.4 MB
    int* counts  = (int*)(p_dst + NT);                        // 200 KB
    int* offsets = counts + N_NODES;                          // 200 KB (+1)
    int* cursor  = offsets + N_NODES + 1;                     // 200 KB
    int* bucket  = cursor + N_NODES;                          // 3.2 MB
    int* flags   = bucket + N_EDGES;                          // 8 B

    detect_kernel<<<1, 64, 0, stream>>>(x, ei, flags);
    hipMemsetAsync(counts, 0, (size_t)N_NODES * sizeof(int), stream);

    const int EB = (N_EDGES + 255) / 256;  // 3125
    hist_kernel<<<EB, 256, 0, stream>>>(ei, counts, flags);
    scan_kernel<<<1, 1024, 0, stream>>>(counts, offsets, cursor);
    fill_kernel<<<EB, 256, 0, stream>>>(ei, cursor, bucket, flags);

    {   // 64 nodes per block (4 waves x 16)
        int blocks = (N_NODES + 63) / 64;   // 782
        node_kernel<<<blocks, 256, 0, stream>>>(x, offsets, bucket,
                                                W_enc, b_enc, W1,
                                                p_src, p_dst, flags);
    }
    {   // 16 threads per edge
        long long threads = (long long)N_EDGES * 16;
        int blocks = (int)((threads + 255) / 256);  // 50000
        edge_kernel<<<blocks, 256, 0, stream>>>(ei, p_src, p_dst,
                                                b1, W2, b2, d_out, flags);
    }
}

// Round 4
// 391.326 us; speedup vs baseline: 1.3725x; 1.3534x over previous
//
#include <hip/hip_runtime.h>
#include <hip/hip_bf16.h>

#define N_NODES 50000
#define N_EDGES 800000
#define D 64
#define VROWS 50048   // 782 tiles * 64 rows, rounded up for unmasked A-loads

typedef __hip_bfloat16 bf16;
typedef __bf16 bf16x8 __attribute__((ext_vector_type(8)));
typedef float  f32x4  __attribute__((ext_vector_type(4)));

__device__ __forceinline__ float b2f(bf16 v) { return __bfloat162float(v); }
__device__ __forceinline__ float bu2f(unsigned short u) {
    unsigned int w = ((unsigned int)u) << 16;
    return __builtin_bit_cast(float, w);
}
__device__ __forceinline__ unsigned short f2bu(float f) {
    bf16 h = __float2bfloat16(f);           // RTNE
    return __builtin_bit_cast(unsigned short, h);
}
// dual-dtype float load: f32mode ? f32[i] : bf16[i]
__device__ __forceinline__ float ldf(const void* p, size_t i, bool f32mode) {
    if (f32mode) return ((const float*)p)[i];
    return b2f(((const bf16*)p)[i]);
}
__device__ __forceinline__ void stf(void* p, size_t i, float v, bool f32mode) {
    if (f32mode) ((float*)p)[i] = v;
    else ((bf16*)p)[i] = __float2bfloat16(v);
}
// dual-width index load: row 0 = src, row 1 = dst
__device__ __forceinline__ int ldidx(const int* ei, size_t e, int row, bool i64mode) {
    if (i64mode) return ei[((size_t)row * N_EDGES + e) * 2];  // low word, LE
    return ei[(size_t)row * N_EDGES + e];
}
__device__ __forceinline__ void unpack8(uint4 v, float* f) {
    f[0] = bu2f(v.x & 0xffff); f[1] = bu2f(v.x >> 16);
    f[2] = bu2f(v.y & 0xffff); f[3] = bu2f(v.y >> 16);
    f[4] = bu2f(v.z & 0xffff); f[5] = bu2f(v.z >> 16);
    f[6] = bu2f(v.w & 0xffff); f[7] = bu2f(v.w >> 16);
}

// ---------------------------------------------------------------------------
// Kernel 0: dtype detection (proven R2/R3) + pre-pack small weights.
// flags[0]=f32?, flags[1]=i64?  w2bf: W2 as bf16[64]; b1f/b2f: f32.
// ---------------------------------------------------------------------------
__global__ void detect_kernel(const void* __restrict__ x,
                              const int* __restrict__ ei,
                              const void* __restrict__ W2,
                              const void* __restrict__ b1,
                              const void* __restrict__ b2,
                              int* __restrict__ flags,
                              unsigned short* __restrict__ w2bf,
                              float* __restrict__ b1f,
                              float* __restrict__ b2f)
{
    if (blockIdx.x != 0 || threadIdx.x != 0) return;
    const unsigned short* u = (const unsigned short*)x;
    int weird = 0;
    for (int k = 0; k < 128; ++k) {
        int ex = (u[2 * k] >> 7) & 0xFF;
        if (ex < 90 || ex > 160) ++weird;
    }
    bool f32m = (weird > 32);
    flags[0] = f32m ? 1 : 0;
    int zeros = 0;
    for (int k = 0; k < 128; ++k) if (ei[2 * k + 1] == 0) ++zeros;
    flags[1] = (zeros > 120) ? 1 : 0;
    for (int k = 0; k < 64; ++k) {
        w2bf[k] = f2bu(ldf(W2, k, f32m));
        b1f[k]  = ldf(b1, k, f32m);
    }
    b2f[0] = ldf(b2, 0, f32m);
}

// ---------------------------------------------------------------------------
// Kernel 1: in-degree histogram
// ---------------------------------------------------------------------------
__global__ __launch_bounds__(256) void hist_kernel(
    const int* __restrict__ ei, int* __restrict__ counts,
    const int* __restrict__ flags)
{
    bool i64m = flags[1] != 0;
    int e = blockIdx.x * 256 + threadIdx.x;
    if (e >= N_EDGES) return;
    atomicAdd(&counts[ldidx(ei, e, 1, i64m)], 1);
}

// ---------------------------------------------------------------------------
// Kernel 2: single-block exclusive scan (proven R3)
// ---------------------------------------------------------------------------
__global__ __launch_bounds__(1024) void scan_kernel(
    const int* __restrict__ counts, int* __restrict__ offsets,
    int* __restrict__ cursor)
{
    __shared__ int sums[1024];
    const int CHUNK = 49;
    int tid = threadIdx.x;
    int start = tid * CHUNK;
    int end   = min(start + CHUNK, N_NODES);
    int local = 0;
    for (int i = start; i < end; ++i) local += counts[i];
    sums[tid] = local;
    __syncthreads();
    for (int off = 1; off < 1024; off <<= 1) {
        int v = (tid >= off) ? sums[tid - off] : 0;
        __syncthreads();
        if (tid >= off) sums[tid] += v;
        __syncthreads();
    }
    int run = sums[tid] - local;
    for (int i = start; i < end; ++i) {
        offsets[i] = run;
        cursor[i]  = run;
        run += counts[i];
    }
    if (tid == 1023) offsets[N_NODES] = sums[1023];
}

// ---------------------------------------------------------------------------
// Kernel 3: bucket fill — spair[pos] = (src(e), e), grouped by dst(e)
// ---------------------------------------------------------------------------
__global__ __launch_bounds__(256) void fill_kernel(
    const int* __restrict__ ei, int* __restrict__ cursor,
    int2* __restrict__ spair, const int* __restrict__ flags)
{
    bool i64m = flags[1] != 0;
    int e = blockIdx.x * 256 + threadIdx.x;
    if (e >= N_EDGES) return;
    int s = ldidx(ei, e, 0, i64m);
    int d = ldidx(ei, e, 1, i64m);
    int pos = atomicAdd(&cursor[d], 1);
    spair[pos] = make_int2(s, e);
}

// ---------------------------------------------------------------------------
// Kernel 4: gather — v[n] = x[n] + sum_{in-edges} x[src]. One wave per node,
// lane = feature, 8 independent accumulators (8 row-loads in flight), no LDS.
// Writes bf16 v-rows into vtab (aliased with p_src storage).
// ---------------------------------------------------------------------------
__global__ __launch_bounds__(256) void gather_kernel(
    const void* __restrict__ x,
    const int* __restrict__ offsets, const int2* __restrict__ spair,
    unsigned short* __restrict__ vtab, const int* __restrict__ flags)
{
    bool f32m = flags[0] != 0;
    int w    = (blockIdx.x * 256 + threadIdx.x) >> 6;   // node id
    int lane = threadIdx.x & 63;
    if (w >= N_NODES) return;
    int beg = offsets[w], end = offsets[w + 1];

    float a0 = ldf(x, (size_t)w * D + lane, f32m);
    float a1 = 0.f, a2 = 0.f, a3 = 0.f, a4 = 0.f, a5 = 0.f, a6 = 0.f, a7 = 0.f;
    int j = beg;
    for (; j + 8 <= end; j += 8) {
        int s0 = spair[j + 0].x, s1 = spair[j + 1].x;
        int s2 = spair[j + 2].x, s3 = spair[j + 3].x;
        int s4 = spair[j + 4].x, s5 = spair[j + 5].x;
        int s6 = spair[j + 6].x, s7 = spair[j + 7].x;
        a0 += ldf(x, (size_t)s0 * D + lane, f32m);
        a1 += ldf(x, (size_t)s1 * D + lane, f32m);
        a2 += ldf(x, (size_t)s2 * D + lane, f32m);
        a3 += ldf(x, (size_t)s3 * D + lane, f32m);
        a4 += ldf(x, (size_t)s4 * D + lane, f32m);
        a5 += ldf(x, (size_t)s5 * D + lane, f32m);
        a6 += ldf(x, (size_t)s6 * D + lane, f32m);
        a7 += ldf(x, (size_t)s7 * D + lane, f32m);
    }
    for (; j < end; ++j)
        a0 += ldf(x, (size_t)spair[j].x * D + lane, f32m);
    float v = ((a0 + a1) + (a2 + a3)) + ((a4 + a5) + (a6 + a7));
    vtab[(size_t)w * D + lane] = f2bu(v);
}

// ---------------------------------------------------------------------------
// Kernel 5: MFMA node transform. One wave = 16 nodes.
//   emb   = relu(V @ W_enc + b_enc)
//   p_src = emb @ W1[0:64]  + b1   (b1 folded here, bf16 out)
//   p_dst = emb @ W1[64:128]       (bf16 out)
// A-fragments load straight from global vtab (16B/lane, contiguous tiles).
// NOTE: vtab aliases p_src — each wave reads only its own 16 rows before
// overwriting them (load->mfma->store dependency chain). No __restrict__.
// ---------------------------------------------------------------------------
__global__ __launch_bounds__(256) void nodemm_kernel(
    const unsigned short* vtab,
    const void* __restrict__ W_enc, const void* __restrict__ b_enc,
    const void* __restrict__ W1,
    unsigned short* p_src, unsigned short* p_dst,
    const float* __restrict__ b1f, const int* __restrict__ flags)
{
    __shared__ unsigned short wtWe[64 * 72];
    __shared__ unsigned short wtWa[64 * 72];
    __shared__ unsigned short wtWb[64 * 72];
    __shared__ float benc[64];
    __shared__ unsigned short ebuf[4][16 * 72];

    bool f32m = flags[0] != 0;
    int tid = threadIdx.x;
    for (int t = tid; t < 4096; t += 256) {
        int i = t >> 6, j = t & 63;             // W[i][j], i=k(in), j=n(out)
        wtWe[j * 72 + i] = f2bu(ldf(W_enc, t, f32m));
        wtWa[j * 72 + i] = f2bu(ldf(W1, t, f32m));
        wtWb[j * 72 + i] = f2bu(ldf(W1, 4096 + t, f32m));
    }
    if (tid < 64) benc[tid] = ldf(b_enc, tid, f32m);
    __syncthreads();

    int wave = tid >> 6;
    int lane = tid & 63;
    int lo   = lane & 15;
    int quad = lane >> 4;
    unsigned short* eb = ebuf[wave];
    int base = blockIdx.x * 64 + wave * 16;

    // A_v straight from global (rows < VROWS always valid)
    bf16x8 av0 = *(const bf16x8*)&vtab[(size_t)(base + lo) * D + quad * 8];
    bf16x8 av1 = *(const bf16x8*)&vtab[(size_t)(base + lo) * D + 32 + quad * 8];

    f32x4 z = {0.f, 0.f, 0.f, 0.f};
    f32x4 acc1[4] = {z, z, z, z};
    #pragma unroll
    for (int nt = 0; nt < 4; ++nt) {
        bf16x8 b0 = *(const bf16x8*)&wtWe[(nt * 16 + lo) * 72 + quad * 8];
        bf16x8 b1v = *(const bf16x8*)&wtWe[(nt * 16 + lo) * 72 + 32 + quad * 8];
        acc1[nt] = __builtin_amdgcn_mfma_f32_16x16x32_bf16(av0, b0, acc1[nt], 0, 0, 0);
        acc1[nt] = __builtin_amdgcn_mfma_f32_16x16x32_bf16(av1, b1v, acc1[nt], 0, 0, 0);
    }
    #pragma unroll
    for (int nt = 0; nt < 4; ++nt) {
        float bias = benc[nt * 16 + lo];
        #pragma unroll
        for (int r = 0; r < 4; ++r) {
            int m = quad * 4 + r;
            float ev = fmaxf(acc1[nt][r] + bias, 0.f);
            eb[m * 72 + nt * 16 + lo] = f2bu(ev);
        }
    }

    bf16x8 ae0 = *(const bf16x8*)&eb[lo * 72 + quad * 8];
    bf16x8 ae1 = *(const bf16x8*)&eb[lo * 72 + 32 + quad * 8];

    f32x4 acc2[4] = {z, z, z, z};
    f32x4 acc3[4] = {z, z, z, z};
    #pragma unroll
    for (int nt = 0; nt < 4; ++nt) {
        bf16x8 ba0 = *(const bf16x8*)&wtWa[(nt * 16 + lo) * 72 + quad * 8];
        bf16x8 ba1 = *(const bf16x8*)&wtWa[(nt * 16 + lo) * 72 + 32 + quad * 8];
        bf16x8 bb0 = *(const bf16x8*)&wtWb[(nt * 16 + lo) * 72 + quad * 8];
        bf16x8 bb1 = *(const bf16x8*)&wtWb[(nt * 16 + lo) * 72 + 32 + quad * 8];
        acc2[nt] = __builtin_amdgcn_mfma_f32_16x16x32_bf16(ae0, ba0, acc2[nt], 0, 0, 0);
        acc2[nt] = __builtin_amdgcn_mfma_f32_16x16x32_bf16(ae1, ba1, acc2[nt], 0, 0, 0);
        acc3[nt] = __builtin_amdgcn_mfma_f32_16x16x32_bf16(ae0, bb0, acc3[nt], 0, 0, 0);
        acc3[nt] = __builtin_amdgcn_mfma_f32_16x16x32_bf16(ae1, bb1, acc3[nt], 0, 0, 0);
    }
    #pragma unroll
    for (int nt = 0; nt < 4; ++nt) {
        float b1v = b1f[nt * 16 + lo];
        #pragma unroll
        for (int r = 0; r < 4; ++r) {
            int node = base + quad * 4 + r;
            if (node < N_NODES) {
                size_t idx = (size_t)node * D + nt * 16 + lo;
                p_src[idx] = f2bu(acc2[nt][r] + b1v);   // fold b1
                p_dst[idx] = f2bu(acc3[nt][r]);
            }
        }
    }
}

// ---------------------------------------------------------------------------
// Kernel 6: edge scorer, dst-grouped. One wave per dst node; 8 lanes/edge;
// p_dst row + W2 loaded ONCE per node; p_src gathered per edge.
//   out[e] = sum_k relu(p_src[s][k] + p_dst[d][k]) * W2[k] + b2   (b1 in p_src)
// ---------------------------------------------------------------------------
__global__ __launch_bounds__(256) void edge_kernel(
    const unsigned short* __restrict__ p_src,
    const unsigned short* __restrict__ p_dst,
    const int* __restrict__ offsets, const int2* __restrict__ spair,
    const unsigned short* __restrict__ w2bf, const float* __restrict__ b2f,
    void* __restrict__ out, const int* __restrict__ flags)
{
    bool f32m = flags[0] != 0;
    int w    = (blockIdx.x * 256 + threadIdx.x) >> 6;   // dst node id
    int lane = threadIdx.x & 63;
    if (w >= N_NODES) return;
    int beg = offsets[w], end = offsets[w + 1];
    if (beg == end) return;

    int sub = lane & 7;    // feature chunk (8 feats)
    int g   = lane >> 3;   // edge slot within round

    uint4 pdv = ((const uint4*)p_dst)[(size_t)w * 8 + sub];
    uint4 w2v = ((const uint4*)w2bf)[sub];
    float pd[8], w2[8];
    unpack8(pdv, pd);
    unpack8(w2v, w2);
    float bb = b2f[0];

    for (int pos0 = beg; pos0 < end; pos0 += 8) {
        int pos = pos0 + g;
        int s = 0, eid = -1;
        if (pos < end) { int2 se = spair[pos]; s = se.x; eid = se.y; }
        uint4 psv = ((const uint4*)p_src)[(size_t)s * 8 + sub];
        float ps[8];
        unpack8(psv, ps);
        float c = 0.f;
        #pragma unroll
        for (int i = 0; i < 8; ++i)
            c += fmaxf(ps[i] + pd[i], 0.f) * w2[i];
        c += __shfl_xor(c, 1, 64);
        c += __shfl_xor(c, 2, 64);
        c += __shfl_xor(c, 4, 64);
        if (sub == 0 && eid >= 0) stf(out, eid, c + bb, f32m);
    }
}

// ---------------------------------------------------------------------------
extern "C" void kernel_launch(void* const* d_in, const int* in_sizes, int n_in,
                              void* d_out, int out_size, void* d_ws, size_t ws_size,
                              hipStream_t stream)
{
    const void* x     = d_in[0];
    const int*  ei    = (const int*)d_in[1];
    const void* W_enc = d_in[2];
    const void* b_enc = d_in[3];
    const void* W1    = d_in[4];
    const void* b1    = d_in[5];
    const void* W2    = d_in[6];
    const void* b2    = d_in[7];

    const size_t NTv = (size_t)VROWS * D;   // 3,203,072 elements
    // ws layout (~19.8 MB):
    unsigned short* p_src = (unsigned short*)d_ws;       // 6.41 MB (aliases vtab)
    unsigned short* p_dst = p_src + NTv;                 // 6.41 MB
    int2*  spair   = (int2*)(p_dst + NTv);               // 6.4 MB
    float* b1f     = (float*)(spair + N_EDGES);          // 256 B
    unsigned short* w2bf = (unsigned short*)(b1f + 64);  // 128 B (16B-aligned)
    float* b2f     = (float*)(w2bf + 64);                // 16 B
    int*   counts  = (int*)(b2f + 4);                    // 200 KB
    int*   offsets = counts + N_NODES;                   // 200 KB (+1)
    int*   cursor  = offsets + N_NODES + 1;              // 200 KB
    int*   flags   = cursor + N_NODES;                   // 8 B

    unsigned short* vtab = p_src;   // alias: v-rows live here until nodemm

    detect_kernel<<<1, 64, 0, stream>>>(x, ei, W2, b1, b2, flags, w2bf, b1f, b2f);
    hipMemsetAsync(counts, 0, (size_t)N_NODES * sizeof(int), stream);

    const int EB = (N_EDGES + 255) / 256;  // 3125
    hist_kernel<<<EB, 256, 0, stream>>>(ei, counts, flags);
    scan_kernel<<<1, 1024, 0, stream>>>(counts, offsets, cursor);
    fill_kernel<<<EB, 256, 0, stream>>>(ei, cursor, spair, flags);

    const int NWB = (N_NODES * 64 + 255) / 256;  // 12500 (1 wave/node)
    gather_kernel<<<NWB, 256, 0, stream>>>(x, offsets, spair, vtab, flags);
    nodemm_kernel<<<(N_NODES + 63) / 64, 256, 0, stream>>>(vtab, W_enc, b_enc, W1,
                                                           p_src, p_dst, b1f, flags);
    edge_kernel<<<NWB, 256, 0, stream>>>(p_src, p_dst, offsets, spair,
                                         w2bf, b2f, d_out, flags);
}

// Round 5
// 269.289 us; speedup vs baseline: 1.9945x; 1.4532x over previous
//
#include <hip/hip_runtime.h>
#include <hip/hip_bf16.h>

#define N_NODES 50000
#define N_EDGES 800000
#define D 64
#define VROWS 50048   // 782 tiles * 64 rows, rounded up for unmasked A-loads
#define NBLK 196      // ceil(N_NODES / 256)

typedef __hip_bfloat16 bf16;
typedef __bf16 bf16x8 __attribute__((ext_vector_type(8)));
typedef float  f32x4  __attribute__((ext_vector_type(4)));

__device__ __forceinline__ float b2f(bf16 v) { return __bfloat162float(v); }
__device__ __forceinline__ float bu2f(unsigned short u) {
    unsigned int w = ((unsigned int)u) << 16;
    return __builtin_bit_cast(float, w);
}
__device__ __forceinline__ unsigned short f2bu(float f) {
    bf16 h = __float2bfloat16(f);           // RTNE
    return __builtin_bit_cast(unsigned short, h);
}
// dual-dtype float load: f32mode ? f32[i] : bf16[i]
__device__ __forceinline__ float ldf(const void* p, size_t i, bool f32mode) {
    if (f32mode) return ((const float*)p)[i];
    return b2f(((const bf16*)p)[i]);
}
__device__ __forceinline__ void stf(void* p, size_t i, float v, bool f32mode) {
    if (f32mode) ((float*)p)[i] = v;
    else ((bf16*)p)[i] = __float2bfloat16(v);
}
// dual-width index load: row 0 = src, row 1 = dst
__device__ __forceinline__ int ldidx(const int* ei, size_t e, int row, bool i64mode) {
    if (i64mode) return ei[((size_t)row * N_EDGES + e) * 2];  // low word, LE
    return ei[(size_t)row * N_EDGES + e];
}
__device__ __forceinline__ void unpack8(uint4 v, float* f) {
    f[0] = bu2f(v.x & 0xffff); f[1] = bu2f(v.x >> 16);
    f[2] = bu2f(v.y & 0xffff); f[3] = bu2f(v.y >> 16);
    f[4] = bu2f(v.z & 0xffff); f[5] = bu2f(v.z >> 16);
    f[6] = bu2f(v.w & 0xffff); f[7] = bu2f(v.w >> 16);
}

// ---------------------------------------------------------------------------
// Kernel 0: dtype detection (proven R2-R4), now 1 wave instead of 1 thread.
// flags[0]=f32?, flags[1]=i64?  w2bf: W2 as bf16[64]; b1f/b2fp: f32.
// ---------------------------------------------------------------------------
__global__ void detect_kernel(const void* __restrict__ x,
                              const int* __restrict__ ei,
                              const void* __restrict__ W2,
                              const void* __restrict__ b1,
                              const void* __restrict__ b2,
                              int* __restrict__ flags,
                              unsigned short* __restrict__ w2bf,
                              float* __restrict__ b1f,
                              float* __restrict__ b2fp)
{
    int lane = threadIdx.x;   // <<<1,64>>>
    const unsigned short* u = (const unsigned short*)x;
    int weird = 0, zeros = 0;
    #pragma unroll
    for (int k = lane; k < 128; k += 64) {
        int ex = (u[2 * k] >> 7) & 0xFF;
        if (ex < 90 || ex > 160) ++weird;
        if (ei[2 * k + 1] == 0) ++zeros;
    }
    #pragma unroll
    for (int off = 1; off < 64; off <<= 1) {
        weird += __shfl_xor(weird, off, 64);
        zeros += __shfl_xor(zeros, off, 64);
    }
    bool f32m = (weird > 32);
    if (lane == 0) {
        flags[0] = f32m ? 1 : 0;
        flags[1] = (zeros > 120) ? 1 : 0;
        b2fp[0] = ldf(b2, 0, f32m);
    }
    w2bf[lane] = f2bu(ldf(W2, lane, f32m));
    b1f[lane]  = ldf(b1, lane, f32m);
}

// ---------------------------------------------------------------------------
// Kernel 1: in-degree histogram
// ---------------------------------------------------------------------------
__global__ __launch_bounds__(256) void hist_kernel(
    const int* __restrict__ ei, int* __restrict__ counts,
    const int* __restrict__ flags)
{
    bool i64m = flags[1] != 0;
    int e = blockIdx.x * 256 + threadIdx.x;
    if (e >= N_EDGES) return;
    atomicAdd(&counts[ldidx(ei, e, 1, i64m)], 1);
}

// ---------------------------------------------------------------------------
// Kernels 2a/2b/2c: three-stage parallel exclusive scan of counts[50000].
// R4 post-mortem: single-block scan was 111 us (one CU). Three tiny parallel
// stages are each launch-overhead-bound (~3-5 us).
// ---------------------------------------------------------------------------
__global__ __launch_bounds__(256) void scan1_kernel(
    const int* __restrict__ counts, int* __restrict__ partials)
{
    int tid = threadIdx.x;
    int i = blockIdx.x * 256 + tid;
    int v = (i < N_NODES) ? counts[i] : 0;
    #pragma unroll
    for (int off = 1; off < 64; off <<= 1) v += __shfl_xor(v, off, 64);
    __shared__ int ws[4];
    if ((tid & 63) == 0) ws[tid >> 6] = v;
    __syncthreads();
    if (tid == 0) partials[blockIdx.x] = ws[0] + ws[1] + ws[2] + ws[3];
}

__global__ __launch_bounds__(256) void scan2_kernel(
    int* __restrict__ partials, int* __restrict__ offsets)
{
    __shared__ int s[256];
    int tid = threadIdx.x;
    int v = (tid < NBLK) ? partials[tid] : 0;
    s[tid] = v;
    __syncthreads();
    for (int off = 1; off < 256; off <<= 1) {
        int t = (tid >= off) ? s[tid - off] : 0;
        __syncthreads();
        s[tid] += t;
        __syncthreads();
    }
    if (tid < NBLK) partials[tid] = s[tid] - v;   // exclusive block base
    if (tid == 255) offsets[N_NODES] = s[255];    // total (= N_EDGES)
}

__global__ __launch_bounds__(256) void scan3_kernel(
    const int* __restrict__ counts, const int* __restrict__ partials,
    int* __restrict__ offsets, int* __restrict__ cursor)
{
    __shared__ int s[256];
    int tid = threadIdx.x;
    int i = blockIdx.x * 256 + tid;
    int v = (i < N_NODES) ? counts[i] : 0;
    s[tid] = v;
    __syncthreads();
    for (int off = 1; off < 256; off <<= 1) {
        int t = (tid >= off) ? s[tid - off] : 0;
        __syncthreads();
        s[tid] += t;
        __syncthreads();
    }
    if (i < N_NODES) {
        int val = partials[blockIdx.x] + s[tid] - v;   // global exclusive
        offsets[i] = val;
        cursor[i]  = val;
    }
}

// ---------------------------------------------------------------------------
// Kernel 3: bucket fill — spair[pos] = (src(e), e), grouped by dst(e)
// ---------------------------------------------------------------------------
__global__ __launch_bounds__(256) void fill_kernel(
    const int* __restrict__ ei, int* __restrict__ cursor,
    int2* __restrict__ spair, const int* __restrict__ flags)
{
    bool i64m = flags[1] != 0;
    int e = blockIdx.x * 256 + threadIdx.x;
    if (e >= N_EDGES) return;
    int s = ldidx(ei, e, 0, i64m);
    int d = ldidx(ei, e, 1, i64m);
    int pos = atomicAdd(&cursor[d], 1);
    spair[pos] = make_int2(s, e);
}

// ---------------------------------------------------------------------------
// Kernel 4: gather — v[n] = x[n] + sum_{in-edges} x[src]. One wave per node,
// lane = feature, 8 independent accumulators, no LDS.
// ---------------------------------------------------------------------------
__global__ __launch_bounds__(256) void gather_kernel(
    const void* __restrict__ x,
    const int* __restrict__ offsets, const int2* __restrict__ spair,
    unsigned short* __restrict__ vtab, const int* __restrict__ flags)
{
    bool f32m = flags[0] != 0;
    int w    = (blockIdx.x * 256 + threadIdx.x) >> 6;   // node id
    int lane = threadIdx.x & 63;
    if (w >= N_NODES) return;
    int beg = offsets[w], end = offsets[w + 1];

    float a0 = ldf(x, (size_t)w * D + lane, f32m);
    float a1 = 0.f, a2 = 0.f, a3 = 0.f, a4 = 0.f, a5 = 0.f, a6 = 0.f, a7 = 0.f;
    int j = beg;
    for (; j + 8 <= end; j += 8) {
        int s0 = spair[j + 0].x, s1 = spair[j + 1].x;
        int s2 = spair[j + 2].x, s3 = spair[j + 3].x;
        int s4 = spair[j + 4].x, s5 = spair[j + 5].x;
        int s6 = spair[j + 6].x, s7 = spair[j + 7].x;
        a0 += ldf(x, (size_t)s0 * D + lane, f32m);
        a1 += ldf(x, (size_t)s1 * D + lane, f32m);
        a2 += ldf(x, (size_t)s2 * D + lane, f32m);
        a3 += ldf(x, (size_t)s3 * D + lane, f32m);
        a4 += ldf(x, (size_t)s4 * D + lane, f32m);
        a5 += ldf(x, (size_t)s5 * D + lane, f32m);
        a6 += ldf(x, (size_t)s6 * D + lane, f32m);
        a7 += ldf(x, (size_t)s7 * D + lane, f32m);
    }
    for (; j < end; ++j)
        a0 += ldf(x, (size_t)spair[j].x * D + lane, f32m);
    float v = ((a0 + a1) + (a2 + a3)) + ((a4 + a5) + (a6 + a7));
    vtab[(size_t)w * D + lane] = f2bu(v);
}

// ---------------------------------------------------------------------------
// Kernel 5: MFMA node transform. One wave = 16 nodes. (proven R4)
// ---------------------------------------------------------------------------
__global__ __launch_bounds__(256) void nodemm_kernel(
    const unsigned short* vtab,
    const void* __restrict__ W_enc, const void* __restrict__ b_enc,
    const void* __restrict__ W1,
    unsigned short* p_src, unsigned short* p_dst,
    const float* __restrict__ b1f, const int* __restrict__ flags)
{
    __shared__ unsigned short wtWe[64 * 72];
    __shared__ unsigned short wtWa[64 * 72];
    __shared__ unsigned short wtWb[64 * 72];
    __shared__ float benc[64];
    __shared__ unsigned short ebuf[4][16 * 72];

    bool f32m = flags[0] != 0;
    int tid = threadIdx.x;
    for (int t = tid; t < 4096; t += 256) {
        int i = t >> 6, j = t & 63;             // W[i][j], i=k(in), j=n(out)
        wtWe[j * 72 + i] = f2bu(ldf(W_enc, t, f32m));
        wtWa[j * 72 + i] = f2bu(ldf(W1, t, f32m));
        wtWb[j * 72 + i] = f2bu(ldf(W1, 4096 + t, f32m));
    }
    if (tid < 64) benc[tid] = ldf(b_enc, tid, f32m);
    __syncthreads();

    int wave = tid >> 6;
    int lane = tid & 63;
    int lo   = lane & 15;
    int quad = lane >> 4;
    unsigned short* eb = ebuf[wave];
    int base = blockIdx.x * 64 + wave * 16;

    bf16x8 av0 = *(const bf16x8*)&vtab[(size_t)(base + lo) * D + quad * 8];
    bf16x8 av1 = *(const bf16x8*)&vtab[(size_t)(base + lo) * D + 32 + quad * 8];

    f32x4 z = {0.f, 0.f, 0.f, 0.f};
    f32x4 acc1[4] = {z, z, z, z};
    #pragma unroll
    for (int nt = 0; nt < 4; ++nt) {
        bf16x8 b0  = *(const bf16x8*)&wtWe[(nt * 16 + lo) * 72 + quad * 8];
        bf16x8 b1v = *(const bf16x8*)&wtWe[(nt * 16 + lo) * 72 + 32 + quad * 8];
        acc1[nt] = __builtin_amdgcn_mfma_f32_16x16x32_bf16(av0, b0, acc1[nt], 0, 0, 0);
        acc1[nt] = __builtin_amdgcn_mfma_f32_16x16x32_bf16(av1, b1v, acc1[nt], 0, 0, 0);
    }
    #pragma unroll
    for (int nt = 0; nt < 4; ++nt) {
        float bias = benc[nt * 16 + lo];
        #pragma unroll
        for (int r = 0; r < 4; ++r) {
            int m = quad * 4 + r;
            float ev = fmaxf(acc1[nt][r] + bias, 0.f);
            eb[m * 72 + nt * 16 + lo] = f2bu(ev);
        }
    }

    bf16x8 ae0 = *(const bf16x8*)&eb[lo * 72 + quad * 8];
    bf16x8 ae1 = *(const bf16x8*)&eb[lo * 72 + 32 + quad * 8];

    f32x4 acc2[4] = {z, z, z, z};
    f32x4 acc3[4] = {z, z, z, z};
    #pragma unroll
    for (int nt = 0; nt < 4; ++nt) {
        bf16x8 ba0 = *(const bf16x8*)&wtWa[(nt * 16 + lo) * 72 + quad * 8];
        bf16x8 ba1 = *(const bf16x8*)&wtWa[(nt * 16 + lo) * 72 + 32 + quad * 8];
        bf16x8 bb0 = *(const bf16x8*)&wtWb[(nt * 16 + lo) * 72 + quad * 8];
        bf16x8 bb1 = *(const bf16x8*)&wtWb[(nt * 16 + lo) * 72 + 32 + quad * 8];
        acc2[nt] = __builtin_amdgcn_mfma_f32_16x16x32_bf16(ae0, ba0, acc2[nt], 0, 0, 0);
        acc2[nt] = __builtin_amdgcn_mfma_f32_16x16x32_bf16(ae1, ba1, acc2[nt], 0, 0, 0);
        acc3[nt] = __builtin_amdgcn_mfma_f32_16x16x32_bf16(ae0, bb0, acc3[nt], 0, 0, 0);
        acc3[nt] = __builtin_amdgcn_mfma_f32_16x16x32_bf16(ae1, bb1, acc3[nt], 0, 0, 0);
    }
    #pragma unroll
    for (int nt = 0; nt < 4; ++nt) {
        float b1v = b1f[nt * 16 + lo];
        #pragma unroll
        for (int r = 0; r < 4; ++r) {
            int node = base + quad * 4 + r;
            if (node < N_NODES) {
                size_t idx = (size_t)node * D + nt * 16 + lo;
                p_src[idx] = f2bu(acc2[nt][r] + b1v);   // fold b1
                p_dst[idx] = f2bu(acc3[nt][r]);
            }
        }
    }
}

// ---------------------------------------------------------------------------
// Kernel 6: edge scorer, dst-grouped. One wave per dst node; 8 lanes/edge.
// ---------------------------------------------------------------------------
__global__ __launch_bounds__(256) void edge_kernel(
    const unsigned short* __restrict__ p_src,
    const unsigned short* __restrict__ p_dst,
    const int* __restrict__ offsets, const int2* __restrict__ spair,
    const unsigned short* __restrict__ w2bf, const float* __restrict__ b2fp,
    void* __restrict__ out, const int* __restrict__ flags)
{
    bool f32m = flags[0] != 0;
    int w    = (blockIdx.x * 256 + threadIdx.x) >> 6;   // dst node id
    int lane = threadIdx.x & 63;
    if (w >= N_NODES) return;
    int beg = offsets[w], end = offsets[w + 1];
    if (beg == end) return;

    int sub = lane & 7;    // feature chunk (8 feats)
    int g   = lane >> 3;   // edge slot within round

    uint4 pdv = ((const uint4*)p_dst)[(size_t)w * 8 + sub];
    uint4 w2v = ((const uint4*)w2bf)[sub];
    float pd[8], w2[8];
    unpack8(pdv, pd);
    unpack8(w2v, w2);
    float bb = b2fp[0];

    for (int pos0 = beg; pos0 < end; pos0 += 8) {
        int pos = pos0 + g;
        int s = 0, eid = -1;
        if (pos < end) { int2 se = spair[pos]; s = se.x; eid = se.y; }
        uint4 psv = ((const uint4*)p_src)[(size_t)s * 8 + sub];
        float ps[8];
        unpack8(psv, ps);
        float c = 0.f;
        #pragma unroll
        for (int i = 0; i < 8; ++i)
            c += fmaxf(ps[i] + pd[i], 0.f) * w2[i];
        c += __shfl_xor(c, 1, 64);
        c += __shfl_xor(c, 2, 64);
        c += __shfl_xor(c, 4, 64);
        if (sub == 0 && eid >= 0) stf(out, eid, c + bb, f32m);
    }
}

// ---------------------------------------------------------------------------
extern "C" void kernel_launch(void* const* d_in, const int* in_sizes, int n_in,
                              void* d_out, int out_size, void* d_ws, size_t ws_size,
                              hipStream_t stream)
{
    const void* x     = d_in[0];
    const int*  ei    = (const int*)d_in[1];
    const void* W_enc = d_in[2];
    const void* b_enc = d_in[3];
    const void* W1    = d_in[4];
    const void* b1    = d_in[5];
    const void* W2    = d_in[6];
    const void* b2    = d_in[7];

    const size_t NTv = (size_t)VROWS * D;   // 3,203,072 elements
    // ws layout (~19.8 MB):
    unsigned short* p_src = (unsigned short*)d_ws;       // 6.41 MB (aliases vtab)
    unsigned short* p_dst = p_src + NTv;                 // 6.41 MB
    int2*  spair   = (int2*)(p_dst + NTv);               // 6.4 MB
    float* b1f     = (float*)(spair + N_EDGES);          // 256 B
    unsigned short* w2bf = (unsigned short*)(b1f + 64);  // 128 B (16B-aligned)
    float* b2fp    = (float*)(w2bf + 64);                // 16 B
    int*   counts  = (int*)(b2fp + 4);                   // 200 KB
    int*   offsets = counts + N_NODES;                   // 200 KB (+1)
    int*   cursor  = offsets + N_NODES + 1;              // 200 KB
    int*   flags   = cursor + N_NODES;                   // 8 B
    int*   partials = flags + 2;                         // 1 KB (NBLK ints)

    unsigned short* vtab = p_src;   // alias: v-rows live here until nodemm

    detect_kernel<<<1, 64, 0, stream>>>(x, ei, W2, b1, b2, flags, w2bf, b1f, b2fp);
    hipMemsetAsync(counts, 0, (size_t)N_NODES * sizeof(int), stream);

    const int EB = (N_EDGES + 255) / 256;  // 3125
    hist_kernel<<<EB, 256, 0, stream>>>(ei, counts, flags);
    scan1_kernel<<<NBLK, 256, 0, stream>>>(counts, partials);
    scan2_kernel<<<1, 256, 0, stream>>>(partials, offsets);
    scan3_kernel<<<NBLK, 256, 0, stream>>>(counts, partials, offsets, cursor);
    fill_kernel<<<EB, 256, 0, stream>>>(ei, cursor, spair, flags);

    const int NWB = (N_NODES * 64 + 255) / 256;  // 12500 (1 wave/node)
    gather_kernel<<<NWB, 256, 0, stream>>>(x, offsets, spair, vtab, flags);
    nodemm_kernel<<<(N_NODES + 63) / 64, 256, 0, stream>>>(vtab, W_enc, b_enc, W1,
                                                           p_src, p_dst, b1f, flags);
    edge_kernel<<<NWB, 256, 0, stream>>>(p_src, p_dst, offsets, spair,
                                         w2bf, b2fp, d_out, flags);
}

// Round 6
// 252.085 us; speedup vs baseline: 2.1306x; 1.0682x over previous
//
#include <hip/hip_runtime.h>
#include <hip/hip_bf16.h>

#define N_NODES 50000
#define N_EDGES 800000
#define D 64
#define VROWS 50048   // 782 tiles * 64 rows, rounded up for unmasked A-loads
#define NBLK 196      // ceil(N_NODES / 256)

typedef __hip_bfloat16 bf16;
typedef __bf16 bf16x8 __attribute__((ext_vector_type(8)));
typedef float  f32x4  __attribute__((ext_vector_type(4)));

__device__ __forceinline__ float b2f(bf16 v) { return __bfloat162float(v); }
__device__ __forceinline__ float bu2f(unsigned short u) {
    unsigned int w = ((unsigned int)u) << 16;
    return __builtin_bit_cast(float, w);
}
__device__ __forceinline__ unsigned short f2bu(float f) {
    bf16 h = __float2bfloat16(f);           // RTNE
    return __builtin_bit_cast(unsigned short, h);
}
// dual-dtype float load: f32mode ? f32[i] : bf16[i]
__device__ __forceinline__ float ldf(const void* p, size_t i, bool f32mode) {
    if (f32mode) return ((const float*)p)[i];
    return b2f(((const bf16*)p)[i]);
}
__device__ __forceinline__ void stf(void* p, size_t i, float v, bool f32mode) {
    if (f32mode) ((float*)p)[i] = v;
    else ((bf16*)p)[i] = __float2bfloat16(v);
}
// dual-width index load: row 0 = src, row 1 = dst
__device__ __forceinline__ int ldidx(const int* ei, size_t e, int row, bool i64mode) {
    if (i64mode) return ei[((size_t)row * N_EDGES + e) * 2];  // low word, LE
    return ei[(size_t)row * N_EDGES + e];
}
__device__ __forceinline__ void unpack8(uint4 v, float* f) {
    f[0] = bu2f(v.x & 0xffff); f[1] = bu2f(v.x >> 16);
    f[2] = bu2f(v.y & 0xffff); f[3] = bu2f(v.y >> 16);
    f[4] = bu2f(v.z & 0xffff); f[5] = bu2f(v.z >> 16);
    f[6] = bu2f(v.w & 0xffff); f[7] = bu2f(v.w >> 16);
}

// ---------------------------------------------------------------------------
// Kernel 0: dtype detection (proven R2-R5), 1 wave.
// ---------------------------------------------------------------------------
__global__ void detect_kernel(const void* __restrict__ x,
                              const int* __restrict__ ei,
                              const void* __restrict__ W2,
                              const void* __restrict__ b1,
                              const void* __restrict__ b2,
                              int* __restrict__ flags,
                              unsigned short* __restrict__ w2bf,
                              float* __restrict__ b1f,
                              float* __restrict__ b2fp)
{
    int lane = threadIdx.x;   // <<<1,64>>>
    const unsigned short* u = (const unsigned short*)x;
    int weird = 0, zeros = 0;
    #pragma unroll
    for (int k = lane; k < 128; k += 64) {
        int ex = (u[2 * k] >> 7) & 0xFF;
        if (ex < 90 || ex > 160) ++weird;
        if (ei[2 * k + 1] == 0) ++zeros;
    }
    #pragma unroll
    for (int off = 1; off < 64; off <<= 1) {
        weird += __shfl_xor(weird, off, 64);
        zeros += __shfl_xor(zeros, off, 64);
    }
    bool f32m = (weird > 32);
    if (lane == 0) {
        flags[0] = f32m ? 1 : 0;
        flags[1] = (zeros > 120) ? 1 : 0;
        b2fp[0] = ldf(b2, 0, f32m);
    }
    w2bf[lane] = f2bu(ldf(W2, lane, f32m));
    b1f[lane]  = ldf(b1, lane, f32m);
}

// ---------------------------------------------------------------------------
// Kernel 1: in-degree histogram, XCD-sharded.
// R5 post-mortem: counts lines shared across all 8 XCDs. Owner group
// (d>>6)&7 == blockIdx&7 keeps each 64-node chunk's counter lines in ONE
// XCD's L2 (round-robin dispatch heuristic; correctness independent).
// Cost: dst row read 8x (L3-resident).
// ---------------------------------------------------------------------------
__global__ __launch_bounds__(256) void hist_kernel(
    const int* __restrict__ ei, int* __restrict__ counts,
    const int* __restrict__ flags)
{
    bool i64m = flags[1] != 0;
    int grp   = blockIdx.x & 7;
    int e = (blockIdx.x >> 3) * 256 + threadIdx.x;
    if (e >= N_EDGES) return;
    int d = ldidx(ei, e, 1, i64m);
    if (((d >> 6) & 7) != grp) return;
    atomicAdd(&counts[d], 1);
}

// ---------------------------------------------------------------------------
// Kernels 2a/2b/2c: three-stage parallel exclusive scan (proven R5).
// ---------------------------------------------------------------------------
__global__ __launch_bounds__(256) void scan1_kernel(
    const int* __restrict__ counts, int* __restrict__ partials)
{
    int tid = threadIdx.x;
    int i = blockIdx.x * 256 + tid;
    int v = (i < N_NODES) ? counts[i] : 0;
    #pragma unroll
    for (int off = 1; off < 64; off <<= 1) v += __shfl_xor(v, off, 64);
    __shared__ int ws[4];
    if ((tid & 63) == 0) ws[tid >> 6] = v;
    __syncthreads();
    if (tid == 0) partials[blockIdx.x] = ws[0] + ws[1] + ws[2] + ws[3];
}

__global__ __launch_bounds__(256) void scan2_kernel(
    int* __restrict__ partials, int* __restrict__ offsets)
{
    __shared__ int s[256];
    int tid = threadIdx.x;
    int v = (tid < NBLK) ? partials[tid] : 0;
    s[tid] = v;
    __syncthreads();
    for (int off = 1; off < 256; off <<= 1) {
        int t = (tid >= off) ? s[tid - off] : 0;
        __syncthreads();
        s[tid] += t;
        __syncthreads();
    }
    if (tid < NBLK) partials[tid] = s[tid] - v;   // exclusive block base
    if (tid == 255) offsets[N_NODES] = s[255];    // total (= N_EDGES)
}

__global__ __launch_bounds__(256) void scan3_kernel(
    const int* __restrict__ counts, const int* __restrict__ partials,
    int* __restrict__ offsets, int* __restrict__ cursor)
{
    __shared__ int s[256];
    int tid = threadIdx.x;
    int i = blockIdx.x * 256 + tid;
    int v = (i < N_NODES) ? counts[i] : 0;
    s[tid] = v;
    __syncthreads();
    for (int off = 1; off < 256; off <<= 1) {
        int t = (tid >= off) ? s[tid - off] : 0;
        __syncthreads();
        s[tid] += t;
        __syncthreads();
    }
    if (i < N_NODES) {
        int val = partials[blockIdx.x] + s[tid] - v;   // global exclusive
        offsets[i] = val;
        cursor[i]  = val;
    }
}

// ---------------------------------------------------------------------------
// Kernel 3: bucket fill, XCD-sharded (same ownership as hist).
// R5 post-mortem: WRITE_SIZE 52MB for 6.4MB payload = 8x cross-XCD
// partial-line writebacks. One writing XCD per 64-node CSR chunk makes
// spair/cursor writebacks dense.
// ---------------------------------------------------------------------------
__global__ __launch_bounds__(256) void fill_kernel(
    const int* __restrict__ ei, int* __restrict__ cursor,
    int2* __restrict__ spair, const int* __restrict__ flags)
{
    bool i64m = flags[1] != 0;
    int grp   = blockIdx.x & 7;
    int e = (blockIdx.x >> 3) * 256 + threadIdx.x;
    if (e >= N_EDGES) return;
    int d = ldidx(ei, e, 1, i64m);
    if (((d >> 6) & 7) != grp) return;
    int s = ldidx(ei, e, 0, i64m);
    int pos = atomicAdd(&cursor[d], 1);
    spair[pos] = make_int2(s, e);
}

// ---------------------------------------------------------------------------
// Kernel 4: gather — v[n] = x[n] + sum_{in-edges} x[src]. One wave per node,
// lane = feature, 8 independent accumulators, no LDS. (proven R4/R5)
// ---------------------------------------------------------------------------
__global__ __launch_bounds__(256) void gather_kernel(
    const void* __restrict__ x,
    const int* __restrict__ offsets, const int2* __restrict__ spair,
    unsigned short* __restrict__ vtab, const int* __restrict__ flags)
{
    bool f32m = flags[0] != 0;
    int w    = (blockIdx.x * 256 + threadIdx.x) >> 6;   // node id
    int lane = threadIdx.x & 63;
    if (w >= N_NODES) return;
    int beg = offsets[w], end = offsets[w + 1];

    float a0 = ldf(x, (size_t)w * D + lane, f32m);
    float a1 = 0.f, a2 = 0.f, a3 = 0.f, a4 = 0.f, a5 = 0.f, a6 = 0.f, a7 = 0.f;
    int j = beg;
    for (; j + 8 <= end; j += 8) {
        int s0 = spair[j + 0].x, s1 = spair[j + 1].x;
        int s2 = spair[j + 2].x, s3 = spair[j + 3].x;
        int s4 = spair[j + 4].x, s5 = spair[j + 5].x;
        int s6 = spair[j + 6].x, s7 = spair[j + 7].x;
        a0 += ldf(x, (size_t)s0 * D + lane, f32m);
        a1 += ldf(x, (size_t)s1 * D + lane, f32m);
        a2 += ldf(x, (size_t)s2 * D + lane, f32m);
        a3 += ldf(x, (size_t)s3 * D + lane, f32m);
        a4 += ldf(x, (size_t)s4 * D + lane, f32m);
        a5 += ldf(x, (size_t)s5 * D + lane, f32m);
        a6 += ldf(x, (size_t)s6 * D + lane, f32m);
        a7 += ldf(x, (size_t)s7 * D + lane, f32m);
    }
    for (; j < end; ++j)
        a0 += ldf(x, (size_t)spair[j].x * D + lane, f32m);
    float v = ((a0 + a1) + (a2 + a3)) + ((a4 + a5) + (a6 + a7));
    vtab[(size_t)w * D + lane] = f2bu(v);
}

// ---------------------------------------------------------------------------
// Kernel 5: MFMA node transform. One wave = 16 nodes. (proven R4/R5)
// ---------------------------------------------------------------------------
__global__ __launch_bounds__(256) void nodemm_kernel(
    const unsigned short* vtab,
    const void* __restrict__ W_enc, const void* __restrict__ b_enc,
    const void* __restrict__ W1,
    unsigned short* p_src, unsigned short* p_dst,
    const float* __restrict__ b1f, const int* __restrict__ flags)
{
    __shared__ unsigned short wtWe[64 * 72];
    __shared__ unsigned short wtWa[64 * 72];
    __shared__ unsigned short wtWb[64 * 72];
    __shared__ float benc[64];
    __shared__ unsigned short ebuf[4][16 * 72];

    bool f32m = flags[0] != 0;
    int tid = threadIdx.x;
    for (int t = tid; t < 4096; t += 256) {
        int i = t >> 6, j = t & 63;             // W[i][j], i=k(in), j=n(out)
        wtWe[j * 72 + i] = f2bu(ldf(W_enc, t, f32m));
        wtWa[j * 72 + i] = f2bu(ldf(W1, t, f32m));
        wtWb[j * 72 + i] = f2bu(ldf(W1, 4096 + t, f32m));
    }
    if (tid < 64) benc[tid] = ldf(b_enc, tid, f32m);
    __syncthreads();

    int wave = tid >> 6;
    int lane = tid & 63;
    int lo   = lane & 15;
    int quad = lane >> 4;
    unsigned short* eb = ebuf[wave];
    int base = blockIdx.x * 64 + wave * 16;

    bf16x8 av0 = *(const bf16x8*)&vtab[(size_t)(base + lo) * D + quad * 8];
    bf16x8 av1 = *(const bf16x8*)&vtab[(size_t)(base + lo) * D + 32 + quad * 8];

    f32x4 z = {0.f, 0.f, 0.f, 0.f};
    f32x4 acc1[4] = {z, z, z, z};
    #pragma unroll
    for (int nt = 0; nt < 4; ++nt) {
        bf16x8 b0  = *(const bf16x8*)&wtWe[(nt * 16 + lo) * 72 + quad * 8];
        bf16x8 b1v = *(const bf16x8*)&wtWe[(nt * 16 + lo) * 72 + 32 + quad * 8];
        acc1[nt] = __builtin_amdgcn_mfma_f32_16x16x32_bf16(av0, b0, acc1[nt], 0, 0, 0);
        acc1[nt] = __builtin_amdgcn_mfma_f32_16x16x32_bf16(av1, b1v, acc1[nt], 0, 0, 0);
    }
    #pragma unroll
    for (int nt = 0; nt < 4; ++nt) {
        float bias = benc[nt * 16 + lo];
        #pragma unroll
        for (int r = 0; r < 4; ++r) {
            int m = quad * 4 + r;
            float ev = fmaxf(acc1[nt][r] + bias, 0.f);
            eb[m * 72 + nt * 16 + lo] = f2bu(ev);
        }
    }

    bf16x8 ae0 = *(const bf16x8*)&eb[lo * 72 + quad * 8];
    bf16x8 ae1 = *(const bf16x8*)&eb[lo * 72 + 32 + quad * 8];

    f32x4 acc2[4] = {z, z, z, z};
    f32x4 acc3[4] = {z, z, z, z};
    #pragma unroll
    for (int nt = 0; nt < 4; ++nt) {
        bf16x8 ba0 = *(const bf16x8*)&wtWa[(nt * 16 + lo) * 72 + quad * 8];
        bf16x8 ba1 = *(const bf16x8*)&wtWa[(nt * 16 + lo) * 72 + 32 + quad * 8];
        bf16x8 bb0 = *(const bf16x8*)&wtWb[(nt * 16 + lo) * 72 + quad * 8];
        bf16x8 bb1 = *(const bf16x8*)&wtWb[(nt * 16 + lo) * 72 + 32 + quad * 8];
        acc2[nt] = __builtin_amdgcn_mfma_f32_16x16x32_bf16(ae0, ba0, acc2[nt], 0, 0, 0);
        acc2[nt] = __builtin_amdgcn_mfma_f32_16x16x32_bf16(ae1, ba1, acc2[nt], 0, 0, 0);
        acc3[nt] = __builtin_amdgcn_mfma_f32_16x16x32_bf16(ae0, bb0, acc3[nt], 0, 0, 0);
        acc3[nt] = __builtin_amdgcn_mfma_f32_16x16x32_bf16(ae1, bb1, acc3[nt], 0, 0, 0);
    }
    #pragma unroll
    for (int nt = 0; nt < 4; ++nt) {
        float b1v = b1f[nt * 16 + lo];
        #pragma unroll
        for (int r = 0; r < 4; ++r) {
            int node = base + quad * 4 + r;
            if (node < N_NODES) {
                size_t idx = (size_t)node * D + nt * 16 + lo;
                p_src[idx] = f2bu(acc2[nt][r] + b1v);   // fold b1
                p_dst[idx] = f2bu(acc3[nt][r]);
            }
        }
    }
}

// ---------------------------------------------------------------------------
// Kernel 6: edge scorer, dst-grouped. One wave per dst node; 8 lanes/edge.
// (proven R4/R5)
// ---------------------------------------------------------------------------
__global__ __launch_bounds__(256) void edge_kernel(
    const unsigned short* __restrict__ p_src,
    const unsigned short* __restrict__ p_dst,
    const int* __restrict__ offsets, const int2* __restrict__ spair,
    const unsigned short* __restrict__ w2bf, const float* __restrict__ b2fp,
    void* __restrict__ out, const int* __restrict__ flags)
{
    bool f32m = flags[0] != 0;
    int w    = (blockIdx.x * 256 + threadIdx.x) >> 6;   // dst node id
    int lane = threadIdx.x & 63;
    if (w >= N_NODES) return;
    int beg = offsets[w], end = offsets[w + 1];
    if (beg == end) return;

    int sub = lane & 7;    // feature chunk (8 feats)
    int g   = lane >> 3;   // edge slot within round

    uint4 pdv = ((const uint4*)p_dst)[(size_t)w * 8 + sub];
    uint4 w2v = ((const uint4*)w2bf)[sub];
    float pd[8], w2[8];
    unpack8(pdv, pd);
    unpack8(w2v, w2);
    float bb = b2fp[0];

    for (int pos0 = beg; pos0 < end; pos0 += 8) {
        int pos = pos0 + g;
        int s = 0, eid = -1;
        if (pos < end) { int2 se = spair[pos]; s = se.x; eid = se.y; }
        uint4 psv = ((const uint4*)p_src)[(size_t)s * 8 + sub];
        float ps[8];
        unpack8(psv, ps);
        float c = 0.f;
        #pragma unroll
        for (int i = 0; i < 8; ++i)
            c += fmaxf(ps[i] + pd[i], 0.f) * w2[i];
        c += __shfl_xor(c, 1, 64);
        c += __shfl_xor(c, 2, 64);
        c += __shfl_xor(c, 4, 64);
        if (sub == 0 && eid >= 0) stf(out, eid, c + bb, f32m);
    }
}

// ---------------------------------------------------------------------------
extern "C" void kernel_launch(void* const* d_in, const int* in_sizes, int n_in,
                              void* d_out, int out_size, void* d_ws, size_t ws_size,
                              hipStream_t stream)
{
    const void* x     = d_in[0];
    const int*  ei    = (const int*)d_in[1];
    const void* W_enc = d_in[2];
    const void* b_enc = d_in[3];
    const void* W1    = d_in[4];
    const void* b1    = d_in[5];
    const void* W2    = d_in[6];
    const void* b2    = d_in[7];

    const size_t NTv = (size_t)VROWS * D;   // 3,203,072 elements
    // ws layout (~19.8 MB):
    unsigned short* p_src = (unsigned short*)d_ws;       // 6.41 MB (aliases vtab)
    unsigned short* p_dst = p_src + NTv;                 // 6.41 MB
    int2*  spair   = (int2*)(p_dst + NTv);               // 6.4 MB
    float* b1f     = (float*)(spair + N_EDGES);          // 256 B
    unsigned short* w2bf = (unsigned short*)(b1f + 64);  // 128 B (16B-aligned)
    float* b2fp    = (float*)(w2bf + 64);                // 16 B
    int*   counts  = (int*)(b2fp + 4);                   // 200 KB
    int*   offsets = counts + N_NODES;                   // 200 KB (+1)
    int*   cursor  = offsets + N_NODES + 1;              // 200 KB
    int*   flags   = cursor + N_NODES;                   // 8 B
    int*   partials = flags + 2;                         // 1 KB (NBLK ints)

    unsigned short* vtab = p_src;   // alias: v-rows live here until nodemm

    detect_kernel<<<1, 64, 0, stream>>>(x, ei, W2, b1, b2, flags, w2bf, b1f, b2fp);
    hipMemsetAsync(counts, 0, (size_t)N_NODES * sizeof(int), stream);

    const int EB  = (N_EDGES + 255) / 256;  // 3125 chunks
    const int EB8 = EB * 8;                 // 8 XCD groups per chunk
    hist_kernel<<<EB8, 256, 0, stream>>>(ei, counts, flags);
    scan1_kernel<<<NBLK, 256, 0, stream>>>(counts, partials);
    scan2_kernel<<<1, 256, 0, stream>>>(partials, offsets);
    scan3_kernel<<<NBLK, 256, 0, stream>>>(counts, partials, offsets, cursor);
    fill_kernel<<<EB8, 256, 0, stream>>>(ei, cursor, spair, flags);

    const int NWB = (N_NODES * 64 + 255) / 256;  // 12500 (1 wave/node)
    gather_kernel<<<NWB, 256, 0, stream>>>(x, offsets, spair, vtab, flags);
    nodemm_kernel<<<(N_NODES + 63) / 64, 256, 0, stream>>>(vtab, W_enc, b_enc, W1,
                                                           p_src, p_dst, b1f, flags);
    edge_kernel<<<NWB, 256, 0, stream>>>(p_src, p_dst, offsets, spair,
                                         w2bf, b2fp, d_out, flags);
}